// Round 15
// baseline (1042.187 us; speedup 1.0000x reference)
//
#include <hip/hip_runtime.h>

#define NN 50000
#define NE 800000
#define R2 (2 * NN)      // batched rows (graphs A+B)
#define DIM 128
#define PD 64
#define LS (DIM + 4)     // padded LDS row stride (132): free 2-way aliasing only
#define PS (PD + 4)      // padded p/z stride (68)
#define NB1 ((NN + 255) / 256)  // 196 scan blocks per graph

// ---------- CSR build (batched over both graphs) ----------

__global__ void k_deg(const int* __restrict__ dA, const int* __restrict__ dB,
                      int* __restrict__ deg2) {
    int e = blockIdx.x * blockDim.x + threadIdx.x;
    if (e >= 2 * NE) return;
    int g = e >= NE;
    int d = (g ? dB : dA)[e - g * NE];
    atomicAdd(&deg2[g * NN + d], 1);
}

// scan1 also emits nrm2 = rsqrt(deg+1) from the already-loaded deg value
// (k_norm dispatch folded in; saves a launch + a deg2 re-read).
__global__ void k_scan1(const int* __restrict__ deg2, int* __restrict__ excl2,
                        int* __restrict__ bsum2, float* __restrict__ nrm2) {
    __shared__ int wsum[4];
    int g = blockIdx.x >= NB1;
    int lb = blockIdx.x - g * NB1;
    const int* deg = deg2 + g * NN;
    int tid = threadIdx.x;
    int lane = tid & 63, wid = tid >> 6;
    int i = lb * 256 + tid;
    int v = (i < NN) ? deg[i] : 0;
    if (i < NN) nrm2[g * NN + i] = rsqrtf((float)v + 1.0f);
    int s = v;
    for (int o = 1; o < 64; o <<= 1) {
        int t = __shfl_up(s, o, 64);
        if (lane >= o) s += t;
    }
    if (lane == 63) wsum[wid] = s;
    __syncthreads();
    int woff = 0;
    for (int w = 0; w < wid; w++) woff += wsum[w];
    if (i < NN) excl2[g * NN + i] = woff + s - v;
    if (tid == 255) bsum2[g * NB1 + lb] = woff + s;
}

__global__ void k_scan2(int* __restrict__ bsum2) {
    __shared__ int wsum[4];
    int* bsum = bsum2 + blockIdx.x * NB1;
    int tid = threadIdx.x;
    int lane = tid & 63, wid = tid >> 6;
    int v = (tid < NB1) ? bsum[tid] : 0;
    int s = v;
    for (int o = 1; o < 64; o <<= 1) {
        int t = __shfl_up(s, o, 64);
        if (lane >= o) s += t;
    }
    if (lane == 63) wsum[wid] = s;
    __syncthreads();
    int woff = 0;
    for (int w = 0; w < wid; w++) woff += wsum[w];
    if (tid < NB1) bsum[tid] = woff + s - v;
}

// rowptr and cnt both get the row-start offset; cnt then serves as the
// running absolute fill cursor in k_fill (saves a rowptr read per edge).
__global__ void k_scan3(const int* __restrict__ excl2, const int* __restrict__ bsum2,
                        int* __restrict__ rowptr2, int* __restrict__ cnt2) {
    int i = blockIdx.x * blockDim.x + threadIdx.x;
    if (i >= R2) return;
    int g = i >= NN;
    int il = i - g * NN;
    int start = excl2[i] + bsum2[g * NB1 + (il >> 8)];
    rowptr2[g * (NN + 1) + il] = start;
    cnt2[i] = start;
    if (il == 0) rowptr2[g * (NN + 1) + NN] = NE;
}

__global__ void k_fill(const int* __restrict__ eA, const int* __restrict__ eB,
                       const float* __restrict__ nrm2,
                       int* __restrict__ cnt2, int2* __restrict__ edges2) {
    int e = blockIdx.x * blockDim.x + threadIdx.x;
    if (e >= 2 * NE) return;
    int g = e >= NE;
    const int* ei = g ? eB : eA;
    int ee = e - g * NE;
    int s = ei[ee], d = ei[NE + ee];
    const float* nrm = nrm2 + g * NN;
    int pos = atomicAdd(&cnt2[g * NN + d], 1);  // absolute slot (cnt pre-seeded)
    int2 rec;
    rec.x = s;
    rec.y = __float_as_int(nrm[s] * nrm[d]);
    edges2[(size_t)g * NE + pos] = rec;
}

// ---------- aggregation: one wave per node, 8-edge unroll, float4/lane ----------
// R14 verdict: 8-edge unroll vs 4-edge = neutral (-2.7us total, noise) ->
// gather is NOT instruction-latency-bound; 25k blocks of TLP already hide
// L2/L3 latency. It is L2/L3-BW/VMEM-throughput bound. Kept (harmless).
// Remaining gather lever: fusion with k_layer (kills agg2 round-trip).
__global__ void k_gather(const float* __restrict__ x0, const float* __restrict__ x1,
                         const int* __restrict__ rowptr2,
                         const int2* __restrict__ edges2,
                         const float* __restrict__ nrm2, float* __restrict__ agg2) {
    int t = blockIdx.x * blockDim.x + threadIdx.x;
    int n = t >> 6;  // global node 0..2NN
    if (n >= R2) return;
    int g = n >= NN;
    int nl = n - g * NN;
    int lane = t & 63;
    int half = lane >> 5;  // 0 or 1
    int hl = lane & 31;    // lane within half: covers dims hl*4 .. hl*4+3
    const float* x = g ? x1 : x0;
    const int* rowptr = rowptr2 + g * (NN + 1);
    const int2* edges = edges2 + (size_t)g * NE;
    int beg = rowptr[nl], end = rowptr[nl + 1];
    float4 a = {0.f, 0.f, 0.f, 0.f};
    float4 b = {0.f, 0.f, 0.f, 0.f};
    int i = beg;
    for (; i + 7 < end; i += 8) {  // 8 edges per iter, 4 per half-wave
        int2 r0 = edges[i + half];
        int2 r1 = edges[i + 2 + half];
        int2 r2 = edges[i + 4 + half];
        int2 r3 = edges[i + 6 + half];
        float4 v0 = *(const float4*)(x + (size_t)r0.x * DIM + hl * 4);
        float4 v1 = *(const float4*)(x + (size_t)r1.x * DIM + hl * 4);
        float4 v2 = *(const float4*)(x + (size_t)r2.x * DIM + hl * 4);
        float4 v3 = *(const float4*)(x + (size_t)r3.x * DIM + hl * 4);
        float c0 = __int_as_float(r0.y), c1 = __int_as_float(r1.y);
        float c2 = __int_as_float(r2.y), c3 = __int_as_float(r3.y);
        a.x += v0.x * c0 + v1.x * c1;  b.x += v2.x * c2 + v3.x * c3;
        a.y += v0.y * c0 + v1.y * c1;  b.y += v2.y * c2 + v3.y * c3;
        a.z += v0.z * c0 + v1.z * c1;  b.z += v2.z * c2 + v3.z * c3;
        a.w += v0.w * c0 + v1.w * c1;  b.w += v2.w * c2 + v3.w * c3;
    }
    for (; i + 3 < end; i += 4) {  // 4 edges, 2 per half-wave
        int2 r0 = edges[i + half];
        int2 r1 = edges[i + 2 + half];
        float4 v0 = *(const float4*)(x + (size_t)r0.x * DIM + hl * 4);
        float4 v1 = *(const float4*)(x + (size_t)r1.x * DIM + hl * 4);
        float c0 = __int_as_float(r0.y), c1 = __int_as_float(r1.y);
        a.x += v0.x * c0 + v1.x * c1;
        a.y += v0.y * c0 + v1.y * c1;
        a.z += v0.z * c0 + v1.z * c1;
        a.w += v0.w * c0 + v1.w * c1;
    }
    for (; i + 1 < end; i += 2) {  // 2 edges, 1 per half-wave
        int2 r0 = edges[i + half];
        float4 v0 = *(const float4*)(x + (size_t)r0.x * DIM + hl * 4);
        float c0 = __int_as_float(r0.y);
        a.x += v0.x * c0; a.y += v0.y * c0;
        a.z += v0.z * c0; a.w += v0.w * c0;
    }
    if (i < end && half == 0) {  // odd remainder: half 0 only
        int2 r0 = edges[i];
        float4 v0 = *(const float4*)(x + (size_t)r0.x * DIM + hl * 4);
        float c0 = __int_as_float(r0.y);
        a.x += v0.x * c0; a.y += v0.y * c0;
        a.z += v0.z * c0; a.w += v0.w * c0;
    }
    a.x += b.x; a.y += b.y; a.z += b.z; a.w += b.w;
    // merge half-wave partials: lane l <-> lane l^32 hold the same 4 dims
    a.x += __shfl_xor(a.x, 32, 64);
    a.y += __shfl_xor(a.y, 32, 64);
    a.z += __shfl_xor(a.z, 32, 64);
    a.w += __shfl_xor(a.w, 32, 64);
    if (half == 0) {  // self-loop term + store (32 lanes x 16B = full 512B row)
        float nm = nrm2[n];
        float cs = nm * nm;
        float4 xv = *(const float4*)(x + (size_t)nl * DIM + hl * 4);
        float4 o;
        o.x = a.x + xv.x * cs;
        o.y = a.y + xv.y * cs;
        o.z = a.z + xv.z * cs;
        o.w = a.w + xv.w * cs;
        *(float4*)(agg2 + (size_t)n * DIM + hl * 4) = o;
    }
}

// ---------- dense GEMMs ----------
// Measured lessons: R5 VGPR cap on 4-row code => ~1GB spill. R8/R10 LDS weight
// staging => spill. R11 32-row k_layer tile (256thr) => slower (2x weight
// traffic + halved ILP). k_layer stays at the verified 64-row form.

// C[R2][128] = A[R2][128] @ W[128][128] + b  (optional ReLU)
template <int RELU>
__global__ __launch_bounds__(256) void k_layer(const float* __restrict__ A,
                                               const float* __restrict__ W,
                                               const float* __restrict__ b,
                                               float* __restrict__ C) {
    __shared__ float As[64 * LS];  // 33 KB
    int tid = threadIdx.x;
    int tx = tid & 15, ty = tid >> 4;
    int n0 = blockIdx.x * 64;
    {
        const float4* Ag = (const float4*)(A + (size_t)n0 * DIM);
        int lim = (R2 - n0) * (DIM / 4);
        for (int i = tid; i < 64 * DIM / 4; i += 256) {
            float4 v = {0.f, 0.f, 0.f, 0.f};
            if (i < lim) v = Ag[i];
            *(float4*)(As + (i >> 5) * LS + (i & 31) * 4) = v;
        }
    }
    __syncthreads();
    float acc[4][8];
    {
        const float4* bg = (const float4*)(b + tx * 8);
        float4 b0 = bg[0], b1 = bg[1];
        for (int i = 0; i < 4; i++) {
            acc[i][0] = b0.x; acc[i][1] = b0.y; acc[i][2] = b0.z; acc[i][3] = b0.w;
            acc[i][4] = b1.x; acc[i][5] = b1.y; acc[i][6] = b1.z; acc[i][7] = b1.w;
        }
    }
    const float* As0 = As + ty * 4 * LS;
    for (int k = 0; k < DIM; k += 4) {
        float a[4][4];
        *(float4*)a[0] = *(const float4*)(As0 + 0 * LS + k);
        *(float4*)a[1] = *(const float4*)(As0 + 1 * LS + k);
        *(float4*)a[2] = *(const float4*)(As0 + 2 * LS + k);
        *(float4*)a[3] = *(const float4*)(As0 + 3 * LS + k);
#pragma unroll
        for (int kk = 0; kk < 4; kk++) {
            float4 w0 = *(const float4*)(W + (size_t)(k + kk) * DIM + tx * 8);
            float4 w1 = *(const float4*)(W + (size_t)(k + kk) * DIM + tx * 8 + 4);
#pragma unroll
            for (int i = 0; i < 4; i++) {
                float aa = a[i][kk];
                acc[i][0] += aa * w0.x; acc[i][1] += aa * w0.y;
                acc[i][2] += aa * w0.z; acc[i][3] += aa * w0.w;
                acc[i][4] += aa * w1.x; acc[i][5] += aa * w1.y;
                acc[i][6] += aa * w1.z; acc[i][7] += aa * w1.w;
            }
        }
    }
    for (int i = 0; i < 4; i++) {
        int n = n0 + ty * 4 + i;
        if (n >= R2) break;
        float4 o0, o1;
        o0.x = acc[i][0]; o0.y = acc[i][1]; o0.z = acc[i][2]; o0.w = acc[i][3];
        o1.x = acc[i][4]; o1.y = acc[i][5]; o1.z = acc[i][6]; o1.w = acc[i][7];
        if (RELU) {
            o0.x = fmaxf(o0.x, 0.f); o0.y = fmaxf(o0.y, 0.f);
            o0.z = fmaxf(o0.z, 0.f); o0.w = fmaxf(o0.w, 0.f);
            o1.x = fmaxf(o1.x, 0.f); o1.y = fmaxf(o1.y, 0.f);
            o1.z = fmaxf(o1.z, 0.f); o1.w = fmaxf(o1.w, 0.f);
        }
        *(float4*)(C + (size_t)n * DIM + tx * 8) = o0;
        *(float4*)(C + (size_t)n * DIM + tx * 8 + 4) = o1;
    }
}

// Fused head over both graphs: p=relu(h@Wp1+bp1); q=p@Wp2+bp2; z=l2norm(q);
// null = relu([h,z]@Wn1+bn1) @ Wn2 + bn2.
// R6 fusion kept (h@Wp1 + h@Wn1[0:128] in one h-scan).
// R14: 512 threads x 2 rows (was 256 x 4), SAME 64-row tile -> per-block
// weight/LDS traffic unchanged, per-thread regs halve. launch_bounds(512,4)
// caps VGPR at 128 -> 2 blocks/CU = 16 waves/CU (was 8). Unlike R5 the cap is
// comfortable (live set ~60); unlike R11 weight traffic does NOT double.
__global__ __launch_bounds__(512, 4) void k_head(
    const float* __restrict__ h, const float* __restrict__ Wp1,
    const float* __restrict__ bp1, const float* __restrict__ Wp2,
    const float* __restrict__ bp2, const float* __restrict__ Wn1,
    const float* __restrict__ bn1, const float* __restrict__ Wn2,
    const float* __restrict__ bn2, float* __restrict__ oz, float* __restrict__ on) {
    __shared__ float hs[64 * LS];  // 33 KB
    __shared__ float ps[64 * PS];  // 17 KB (p, then reused for z)
    int tid = threadIdx.x;
    int tx = tid & 15, ty = tid >> 4;  // ty 0..31, 2 rows each
    int n0 = blockIdx.x * 64;
    {
        const float4* hg = (const float4*)(h + (size_t)n0 * DIM);
        int lim = (R2 - n0) * (DIM / 4);
        for (int i = tid; i < 64 * DIM / 4; i += 512) {
            float4 v = {0.f, 0.f, 0.f, 0.f};
            if (i < lim) v = hg[i];
            *(float4*)(hs + (i >> 5) * LS + (i & 31) * 4) = v;
        }
    }
    __syncthreads();
    const float* hs0 = hs + ty * 2 * LS;
    float accp[2][4];  // p accumulator (reused for q in phase 2)
    float accn[2][4];  // null-head accumulator, persistent across phases
    // ---- fused phase 1+3a: accp = h @ Wp1 + bp1 ; accn = h @ Wn1[0:128] + bn1
    {
        float4 bv = *(const float4*)(bp1 + tx * 4);
        float4 nv = *(const float4*)(bn1 + tx * 4);
        for (int i = 0; i < 2; i++) {
            accp[i][0] = bv.x; accp[i][1] = bv.y; accp[i][2] = bv.z; accp[i][3] = bv.w;
            accn[i][0] = nv.x; accn[i][1] = nv.y; accn[i][2] = nv.z; accn[i][3] = nv.w;
        }
    }
    for (int k = 0; k < DIM; k += 4) {
        float a[2][4];
        *(float4*)a[0] = *(const float4*)(hs0 + 0 * LS + k);
        *(float4*)a[1] = *(const float4*)(hs0 + 1 * LS + k);
#pragma unroll
        for (int kk = 0; kk < 4; kk++) {
            float4 wp = *(const float4*)(Wp1 + (size_t)(k + kk) * PD + tx * 4);
            float4 wn = *(const float4*)(Wn1 + (size_t)(k + kk) * PD + tx * 4);
#pragma unroll
            for (int i = 0; i < 2; i++) {
                float aa = a[i][kk];
                accp[i][0] += aa * wp.x; accp[i][1] += aa * wp.y;
                accp[i][2] += aa * wp.z; accp[i][3] += aa * wp.w;
                accn[i][0] += aa * wn.x; accn[i][1] += aa * wn.y;
                accn[i][2] += aa * wn.z; accn[i][3] += aa * wn.w;
            }
        }
    }
    for (int i = 0; i < 2; i++) {
        float4 pv;
        pv.x = fmaxf(accp[i][0], 0.f); pv.y = fmaxf(accp[i][1], 0.f);
        pv.z = fmaxf(accp[i][2], 0.f); pv.w = fmaxf(accp[i][3], 0.f);
        *(float4*)(ps + (ty * 2 + i) * PS + tx * 4) = pv;
    }
    __syncthreads();
    // ---- phase 2: q = p @ Wp2 + bp2, row l2norm ----
    {
        float4 bv = *(const float4*)(bp2 + tx * 4);
        for (int i = 0; i < 2; i++) {
            accp[i][0] = bv.x; accp[i][1] = bv.y; accp[i][2] = bv.z; accp[i][3] = bv.w;
        }
    }
    const float* ps0 = ps + ty * 2 * PS;
    for (int k = 0; k < PD; k += 4) {
        float a[2][4];
        *(float4*)a[0] = *(const float4*)(ps0 + 0 * PS + k);
        *(float4*)a[1] = *(const float4*)(ps0 + 1 * PS + k);
#pragma unroll
        for (int kk = 0; kk < 4; kk++) {
            float4 w = *(const float4*)(Wp2 + (size_t)(k + kk) * PD + tx * 4);
#pragma unroll
            for (int i = 0; i < 2; i++) {
                float aa = a[i][kk];
                accp[i][0] += aa * w.x; accp[i][1] += aa * w.y;
                accp[i][2] += aa * w.z; accp[i][3] += aa * w.w;
            }
        }
    }
    float inv[2];
    for (int i = 0; i < 2; i++) {
        float ss = accp[i][0] * accp[i][0] + accp[i][1] * accp[i][1] +
                   accp[i][2] * accp[i][2] + accp[i][3] * accp[i][3];
        ss += __shfl_xor(ss, 1, 16);
        ss += __shfl_xor(ss, 2, 16);
        ss += __shfl_xor(ss, 4, 16);
        ss += __shfl_xor(ss, 8, 16);
        inv[i] = 1.0f / fmaxf(sqrtf(ss), 1e-12f);
    }
    __syncthreads();  // everyone done reading p before z overwrites
    for (int i = 0; i < 2; i++) {
        int n = n0 + ty * 2 + i;
        float4 zv;
        zv.x = accp[i][0] * inv[i]; zv.y = accp[i][1] * inv[i];
        zv.z = accp[i][2] * inv[i]; zv.w = accp[i][3] * inv[i];
        *(float4*)(ps + (ty * 2 + i) * PS + tx * 4) = zv;
        if (n < R2) *(float4*)(oz + (size_t)n * PD + tx * 4) = zv;
    }
    __syncthreads();
    // ---- phase 3b: accn += z @ Wn1[DIM:DIM+64]; null = relu(accn) @ Wn2 + bn2
    for (int k = 0; k < PD; k += 4) {
        float a[2][4];
        *(float4*)a[0] = *(const float4*)(ps0 + 0 * PS + k);
        *(float4*)a[1] = *(const float4*)(ps0 + 1 * PS + k);
#pragma unroll
        for (int kk = 0; kk < 4; kk++) {
            float4 w = *(const float4*)(Wn1 + (size_t)(DIM + k + kk) * PD + tx * 4);
#pragma unroll
            for (int i = 0; i < 2; i++) {
                float aa = a[i][kk];
                accn[i][0] += aa * w.x; accn[i][1] += aa * w.y;
                accn[i][2] += aa * w.z; accn[i][3] += aa * w.w;
            }
        }
    }
    {
        float4 w2 = *(const float4*)(Wn2 + tx * 4);
        float b2v = bn2[0];
        for (int i = 0; i < 2; i++) {
            float r = fmaxf(accn[i][0], 0.f) * w2.x + fmaxf(accn[i][1], 0.f) * w2.y +
                      fmaxf(accn[i][2], 0.f) * w2.z + fmaxf(accn[i][3], 0.f) * w2.w;
            r += __shfl_xor(r, 1, 16);
            r += __shfl_xor(r, 2, 16);
            r += __shfl_xor(r, 4, 16);
            r += __shfl_xor(r, 8, 16);
            int n = n0 + ty * 2 + i;
            if (tx == 0 && n < R2) on[n] = r + b2v;
        }
    }
}

extern "C" void kernel_launch(void* const* d_in, const int* in_sizes, int n_in,
                              void* d_out, int out_size, void* d_ws, size_t ws_size,
                              hipStream_t stream) {
    const float* xA = (const float*)d_in[0];
    const float* xB = (const float*)d_in[1];
    const int* eiA = (const int*)d_in[2];
    const int* eiB = (const int*)d_in[3];
    const float* W1 = (const float*)d_in[4];
    const float* b1 = (const float*)d_in[5];
    const float* W2 = (const float*)d_in[6];
    const float* b2 = (const float*)d_in[7];
    const float* Wp1 = (const float*)d_in[8];
    const float* bp1 = (const float*)d_in[9];
    const float* Wp2 = (const float*)d_in[10];
    const float* bp2 = (const float*)d_in[11];
    const float* Wn1 = (const float*)d_in[12];
    const float* bn1 = (const float*)d_in[13];
    const float* Wn2 = (const float*)d_in[14];
    const float* bn2 = (const float*)d_in[15];

    float* out = (float*)d_out;
    float* outH = out;                            // hA, hB (contiguous 2NN x 128)
    float* outZ = out + (size_t)R2 * DIM;         // zA, zB (contiguous 2NN x 64)
    float* outNull = outZ + (size_t)R2 * PD;      // nullA, nullB (2NN)

    // Workspace (~66 MB), batched over both graphs
    char* w = (char*)d_ws;
    int* deg2 = (int*)w;     w += (((size_t)R2 * 4 + 255) / 256) * 256;
    int* cnt2 = (int*)w;     w += (((size_t)R2 * 4 + 255) / 256) * 256;
    int* excl2 = (int*)w;    w += (((size_t)R2 * 4 + 255) / 256) * 256;
    int* bsum2 = (int*)w;    w += (((size_t)2 * NB1 * 4 + 255) / 256) * 256;
    int* rowptr2 = (int*)w;  w += (((size_t)2 * (NN + 1) * 4 + 255) / 256) * 256;
    float* nrm2 = (float*)w; w += (((size_t)R2 * 4 + 255) / 256) * 256;
    int2* edges2 = (int2*)w; w += (size_t)2 * NE * 8;
    float* agg2 = (float*)w; w += (size_t)R2 * DIM * 4;
    if (ws_size < (size_t)(w - (char*)d_ws)) return;  // tripwire: absmax~0.57

    const int GB = (R2 + 63) / 64;  // 1563 dense tiles

    // CSR build, both graphs in one go
    hipMemsetAsync(deg2, 0, (size_t)R2 * 4, stream);
    k_deg<<<(2 * NE + 255) / 256, 256, 0, stream>>>(eiA + NE, eiB + NE, deg2);
    k_scan1<<<2 * NB1, 256, 0, stream>>>(deg2, excl2, bsum2, nrm2);
    k_scan2<<<2, 256, 0, stream>>>(bsum2);
    k_scan3<<<(R2 + 255) / 256, 256, 0, stream>>>(excl2, bsum2, rowptr2, cnt2);
    k_fill<<<(2 * NE + 255) / 256, 256, 0, stream>>>(eiA, eiB, nrm2, cnt2, edges2);

    // Layer 1: gather (incl. self term) -> dense; h1 lives in the hA/hB region
    k_gather<<<R2 * 64 / 256, 256, 0, stream>>>(xA, xB, rowptr2, edges2, nrm2, agg2);
    k_layer<1><<<GB, 256, 0, stream>>>(agg2, W1, b1, outH);

    // Layer 2: h1 -> h2 in place
    k_gather<<<R2 * 64 / 256, 256, 0, stream>>>(outH, outH + (size_t)NN * DIM,
                                                rowptr2, edges2, nrm2, agg2);
    k_layer<0><<<GB, 256, 0, stream>>>(agg2, W2, b2, outH);

    // Fused projection + null head, both graphs
    k_head<<<GB, 512, 0, stream>>>(outH, Wp1, bp1, Wp2, bp2, Wn1, bn1, Wn2, bn2,
                                   outZ, outNull);
}

// Round 19
// 797.069 us; speedup vs baseline: 1.3075x; 1.3075x over previous
//
#include <hip/hip_runtime.h>

#define NN 50000
#define NE 800000
#define R2 (2 * NN)      // batched rows (graphs A+B)
#define DIM 128
#define PD 64
#define LS (DIM + 4)     // padded LDS row stride (132): free 2-way aliasing only
#define PS (PD + 4)      // padded p/z stride (68)
#define NB1 ((NN + 255) / 256)  // 196 scan blocks per graph

// ---------- CSR build (batched over both graphs) ----------

__global__ void k_deg(const int* __restrict__ dA, const int* __restrict__ dB,
                      int* __restrict__ deg2) {
    int e = blockIdx.x * blockDim.x + threadIdx.x;
    if (e >= 2 * NE) return;
    int g = e >= NE;
    int d = (g ? dB : dA)[e - g * NE];
    atomicAdd(&deg2[g * NN + d], 1);
}

// scan1 also emits nrm2 = rsqrt(deg+1) from the already-loaded deg value
// (k_norm dispatch folded in; saves a launch + a deg2 re-read).
__global__ void k_scan1(const int* __restrict__ deg2, int* __restrict__ excl2,
                        int* __restrict__ bsum2, float* __restrict__ nrm2) {
    __shared__ int wsum[4];
    int g = blockIdx.x >= NB1;
    int lb = blockIdx.x - g * NB1;
    const int* deg = deg2 + g * NN;
    int tid = threadIdx.x;
    int lane = tid & 63, wid = tid >> 6;
    int i = lb * 256 + tid;
    int v = (i < NN) ? deg[i] : 0;
    if (i < NN) nrm2[g * NN + i] = rsqrtf((float)v + 1.0f);
    int s = v;
    for (int o = 1; o < 64; o <<= 1) {
        int t = __shfl_up(s, o, 64);
        if (lane >= o) s += t;
    }
    if (lane == 63) wsum[wid] = s;
    __syncthreads();
    int woff = 0;
    for (int w = 0; w < wid; w++) woff += wsum[w];
    if (i < NN) excl2[g * NN + i] = woff + s - v;
    if (tid == 255) bsum2[g * NB1 + lb] = woff + s;
}

__global__ void k_scan2(int* __restrict__ bsum2) {
    __shared__ int wsum[4];
    int* bsum = bsum2 + blockIdx.x * NB1;
    int tid = threadIdx.x;
    int lane = tid & 63, wid = tid >> 6;
    int v = (tid < NB1) ? bsum[tid] : 0;
    int s = v;
    for (int o = 1; o < 64; o <<= 1) {
        int t = __shfl_up(s, o, 64);
        if (lane >= o) s += t;
    }
    if (lane == 63) wsum[wid] = s;
    __syncthreads();
    int woff = 0;
    for (int w = 0; w < wid; w++) woff += wsum[w];
    if (tid < NB1) bsum[tid] = woff + s - v;
}

// rowptr and cnt both get the row-start offset; cnt then serves as the
// running absolute fill cursor in k_fill (saves a rowptr read per edge).
__global__ void k_scan3(const int* __restrict__ excl2, const int* __restrict__ bsum2,
                        int* __restrict__ rowptr2, int* __restrict__ cnt2) {
    int i = blockIdx.x * blockDim.x + threadIdx.x;
    if (i >= R2) return;
    int g = i >= NN;
    int il = i - g * NN;
    int start = excl2[i] + bsum2[g * NB1 + (il >> 8)];
    rowptr2[g * (NN + 1) + il] = start;
    cnt2[i] = start;
    if (il == 0) rowptr2[g * (NN + 1) + NN] = NE;
}

__global__ void k_fill(const int* __restrict__ eA, const int* __restrict__ eB,
                       const float* __restrict__ nrm2,
                       int* __restrict__ cnt2, int2* __restrict__ edges2) {
    int e = blockIdx.x * blockDim.x + threadIdx.x;
    if (e >= 2 * NE) return;
    int g = e >= NE;
    const int* ei = g ? eB : eA;
    int ee = e - g * NE;
    int s = ei[ee], d = ei[NE + ee];
    const float* nrm = nrm2 + g * NN;
    int pos = atomicAdd(&cnt2[g * NN + d], 1);  // absolute slot (cnt pre-seeded)
    int2 rec;
    rec.x = s;
    rec.y = __float_as_int(nrm[s] * nrm[d]);
    edges2[(size_t)g * NE + pos] = rec;
}

// ---------- R15: FUSED gather + dense layer ----------
// Occupancy attacks on the dense kernels are dead (R5/R8/R15: all spill).
// Instead kill the agg2 round-trip: each 64-row block gathers its nodes
// DIRECTLY into the GEMM's LDS tile (wave w handles 16 nodes sequentially;
// per-node body identical to the old k_gather incl. 8-edge unroll), then runs
// the verified k_layer GEMM body. Saves 51MB write + 51MB read per layer plus
// 2 launches. Buffers re-plumbed to avoid in-place races: layer1 x->h1buf,
// layer2 h1buf->outH (never reads outH).
template <int RELU>
__global__ __launch_bounds__(256) void k_gl(
    const float* __restrict__ x0, const float* __restrict__ x1,
    const int* __restrict__ rowptr2, const int2* __restrict__ edges2,
    const float* __restrict__ nrm2,
    const float* __restrict__ W, const float* __restrict__ b,
    float* __restrict__ C) {
    __shared__ float As[64 * LS];  // 33 KB gathered tile
    int tid = threadIdx.x;
    int lane = tid & 63, wid = tid >> 6;  // 4 waves
    int n0 = blockIdx.x * 64;
    // ---- phase A: gather 16 nodes per wave into As rows ----
    int half = lane >> 5;  // 0/1: even/odd edge of a pair
    int hl = lane & 31;    // dims hl*4 .. hl*4+3
    for (int j = 0; j < 16; j++) {
        int n = n0 + wid * 16 + j;  // wave-uniform
        if (n >= R2) break;         // last block: 32 pad rows (stores guarded)
        int g = n >= NN;
        int nl = n - g * NN;
        const float* x = g ? x1 : x0;
        const int* rowptr = rowptr2 + g * (NN + 1);
        const int2* edges = edges2 + (size_t)g * NE;
        int beg = rowptr[nl], end = rowptr[nl + 1];
        float4 a = {0.f, 0.f, 0.f, 0.f};
        float4 bb = {0.f, 0.f, 0.f, 0.f};
        int i = beg;
        for (; i + 7 < end; i += 8) {  // 8 edges/iter, 4 per half-wave
            int2 r0 = edges[i + half];
            int2 r1 = edges[i + 2 + half];
            int2 r2 = edges[i + 4 + half];
            int2 r3 = edges[i + 6 + half];
            float4 v0 = *(const float4*)(x + (size_t)r0.x * DIM + hl * 4);
            float4 v1 = *(const float4*)(x + (size_t)r1.x * DIM + hl * 4);
            float4 v2 = *(const float4*)(x + (size_t)r2.x * DIM + hl * 4);
            float4 v3 = *(const float4*)(x + (size_t)r3.x * DIM + hl * 4);
            float c0 = __int_as_float(r0.y), c1 = __int_as_float(r1.y);
            float c2 = __int_as_float(r2.y), c3 = __int_as_float(r3.y);
            a.x += v0.x * c0 + v1.x * c1;  bb.x += v2.x * c2 + v3.x * c3;
            a.y += v0.y * c0 + v1.y * c1;  bb.y += v2.y * c2 + v3.y * c3;
            a.z += v0.z * c0 + v1.z * c1;  bb.z += v2.z * c2 + v3.z * c3;
            a.w += v0.w * c0 + v1.w * c1;  bb.w += v2.w * c2 + v3.w * c3;
        }
        for (; i + 3 < end; i += 4) {
            int2 r0 = edges[i + half];
            int2 r1 = edges[i + 2 + half];
            float4 v0 = *(const float4*)(x + (size_t)r0.x * DIM + hl * 4);
            float4 v1 = *(const float4*)(x + (size_t)r1.x * DIM + hl * 4);
            float c0 = __int_as_float(r0.y), c1 = __int_as_float(r1.y);
            a.x += v0.x * c0 + v1.x * c1;
            a.y += v0.y * c0 + v1.y * c1;
            a.z += v0.z * c0 + v1.z * c1;
            a.w += v0.w * c0 + v1.w * c1;
        }
        for (; i + 1 < end; i += 2) {
            int2 r0 = edges[i + half];
            float4 v0 = *(const float4*)(x + (size_t)r0.x * DIM + hl * 4);
            float c0 = __int_as_float(r0.y);
            a.x += v0.x * c0; a.y += v0.y * c0;
            a.z += v0.z * c0; a.w += v0.w * c0;
        }
        if (i < end && half == 0) {
            int2 r0 = edges[i];
            float4 v0 = *(const float4*)(x + (size_t)r0.x * DIM + hl * 4);
            float c0 = __int_as_float(r0.y);
            a.x += v0.x * c0; a.y += v0.y * c0;
            a.z += v0.z * c0; a.w += v0.w * c0;
        }
        a.x += bb.x; a.y += bb.y; a.z += bb.z; a.w += bb.w;
        a.x += __shfl_xor(a.x, 32, 64);
        a.y += __shfl_xor(a.y, 32, 64);
        a.z += __shfl_xor(a.z, 32, 64);
        a.w += __shfl_xor(a.w, 32, 64);
        if (half == 0) {  // self-loop + write LDS row (32 lanes x 16B = 512B)
            float nm = nrm2[n];
            float cs = nm * nm;
            float4 xv = *(const float4*)(x + (size_t)nl * DIM + hl * 4);
            float4 o;
            o.x = a.x + xv.x * cs;
            o.y = a.y + xv.y * cs;
            o.z = a.z + xv.z * cs;
            o.w = a.w + xv.w * cs;
            *(float4*)(As + (n - n0) * LS + hl * 4) = o;
        }
    }
    __syncthreads();
    // ---- phase B: verified k_layer GEMM body (64 rows x 128, acc[4][8]) ----
    int tx = tid & 15, ty = tid >> 4;
    float acc[4][8];
    {
        const float4* bg = (const float4*)(b + tx * 8);
        float4 b0 = bg[0], b1 = bg[1];
        for (int i = 0; i < 4; i++) {
            acc[i][0] = b0.x; acc[i][1] = b0.y; acc[i][2] = b0.z; acc[i][3] = b0.w;
            acc[i][4] = b1.x; acc[i][5] = b1.y; acc[i][6] = b1.z; acc[i][7] = b1.w;
        }
    }
    const float* As0 = As + ty * 4 * LS;
    for (int k = 0; k < DIM; k += 4) {
        float a[4][4];
        *(float4*)a[0] = *(const float4*)(As0 + 0 * LS + k);
        *(float4*)a[1] = *(const float4*)(As0 + 1 * LS + k);
        *(float4*)a[2] = *(const float4*)(As0 + 2 * LS + k);
        *(float4*)a[3] = *(const float4*)(As0 + 3 * LS + k);
#pragma unroll
        for (int kk = 0; kk < 4; kk++) {
            float4 w0 = *(const float4*)(W + (size_t)(k + kk) * DIM + tx * 8);
            float4 w1 = *(const float4*)(W + (size_t)(k + kk) * DIM + tx * 8 + 4);
#pragma unroll
            for (int i = 0; i < 4; i++) {
                float aa = a[i][kk];
                acc[i][0] += aa * w0.x; acc[i][1] += aa * w0.y;
                acc[i][2] += aa * w0.z; acc[i][3] += aa * w0.w;
                acc[i][4] += aa * w1.x; acc[i][5] += aa * w1.y;
                acc[i][6] += aa * w1.z; acc[i][7] += aa * w1.w;
            }
        }
    }
    for (int i = 0; i < 4; i++) {
        int n = n0 + ty * 4 + i;
        if (n >= R2) break;
        float4 o0, o1;
        o0.x = acc[i][0]; o0.y = acc[i][1]; o0.z = acc[i][2]; o0.w = acc[i][3];
        o1.x = acc[i][4]; o1.y = acc[i][5]; o1.z = acc[i][6]; o1.w = acc[i][7];
        if (RELU) {
            o0.x = fmaxf(o0.x, 0.f); o0.y = fmaxf(o0.y, 0.f);
            o0.z = fmaxf(o0.z, 0.f); o0.w = fmaxf(o0.w, 0.f);
            o1.x = fmaxf(o1.x, 0.f); o1.y = fmaxf(o1.y, 0.f);
            o1.w = fmaxf(o1.w, 0.f); o1.z = fmaxf(o1.z, 0.f);
        }
        *(float4*)(C + (size_t)n * DIM + tx * 8) = o0;
        *(float4*)(C + (size_t)n * DIM + tx * 8 + 4) = o1;
    }
}

// Fused head over both graphs: p=relu(h@Wp1+bp1); q=p@Wp2+bp2; z=l2norm(q);
// null = relu([h,z]@Wn1+bn1) @ Wn2 + bn2.
// R6 form, verified 175us three times: 256 thr x 4 rows, h@Wp1 + h@Wn1[0:128]
// fused in one h-scan, weights direct from L2, VGPR=256. Occupancy attacks
// (R5 cap, R8 LDS-stage, R15 512-thr) ALL spilled — do not retry.
__global__ __launch_bounds__(256) void k_head(
    const float* __restrict__ h, const float* __restrict__ Wp1,
    const float* __restrict__ bp1, const float* __restrict__ Wp2,
    const float* __restrict__ bp2, const float* __restrict__ Wn1,
    const float* __restrict__ bn1, const float* __restrict__ Wn2,
    const float* __restrict__ bn2, float* __restrict__ oz, float* __restrict__ on) {
    __shared__ float hs[64 * LS];  // 33 KB
    __shared__ float ps[64 * PS];  // 17 KB (p, then reused for z)
    int tid = threadIdx.x;
    int tx = tid & 15, ty = tid >> 4;
    int n0 = blockIdx.x * 64;
    {
        const float4* hg = (const float4*)(h + (size_t)n0 * DIM);
        int lim = (R2 - n0) * (DIM / 4);
        for (int i = tid; i < 64 * DIM / 4; i += 256) {
            float4 v = {0.f, 0.f, 0.f, 0.f};
            if (i < lim) v = hg[i];
            *(float4*)(hs + (i >> 5) * LS + (i & 31) * 4) = v;
        }
    }
    __syncthreads();
    const float* hs0 = hs + ty * 4 * LS;
    float accp[4][4];  // p accumulator (reused for q in phase 2)
    float accn[4][4];  // null-head accumulator, persistent across phases
    // ---- fused phase 1+3a: accp = h @ Wp1 + bp1 ; accn = h @ Wn1[0:128] + bn1
    {
        float4 bv = *(const float4*)(bp1 + tx * 4);
        float4 nv = *(const float4*)(bn1 + tx * 4);
        for (int i = 0; i < 4; i++) {
            accp[i][0] = bv.x; accp[i][1] = bv.y; accp[i][2] = bv.z; accp[i][3] = bv.w;
            accn[i][0] = nv.x; accn[i][1] = nv.y; accn[i][2] = nv.z; accn[i][3] = nv.w;
        }
    }
    for (int k = 0; k < DIM; k += 4) {
        float a[4][4];
        *(float4*)a[0] = *(const float4*)(hs0 + 0 * LS + k);
        *(float4*)a[1] = *(const float4*)(hs0 + 1 * LS + k);
        *(float4*)a[2] = *(const float4*)(hs0 + 2 * LS + k);
        *(float4*)a[3] = *(const float4*)(hs0 + 3 * LS + k);
#pragma unroll
        for (int kk = 0; kk < 4; kk++) {
            float4 wp = *(const float4*)(Wp1 + (size_t)(k + kk) * PD + tx * 4);
            float4 wn = *(const float4*)(Wn1 + (size_t)(k + kk) * PD + tx * 4);
#pragma unroll
            for (int i = 0; i < 4; i++) {
                float aa = a[i][kk];
                accp[i][0] += aa * wp.x; accp[i][1] += aa * wp.y;
                accp[i][2] += aa * wp.z; accp[i][3] += aa * wp.w;
                accn[i][0] += aa * wn.x; accn[i][1] += aa * wn.y;
                accn[i][2] += aa * wn.z; accn[i][3] += aa * wn.w;
            }
        }
    }
    for (int i = 0; i < 4; i++) {
        float4 pv;
        pv.x = fmaxf(accp[i][0], 0.f); pv.y = fmaxf(accp[i][1], 0.f);
        pv.z = fmaxf(accp[i][2], 0.f); pv.w = fmaxf(accp[i][3], 0.f);
        *(float4*)(ps + (ty * 4 + i) * PS + tx * 4) = pv;
    }
    __syncthreads();
    // ---- phase 2: q = p @ Wp2 + bp2, row l2norm ----
    {
        float4 bv = *(const float4*)(bp2 + tx * 4);
        for (int i = 0; i < 4; i++) {
            accp[i][0] = bv.x; accp[i][1] = bv.y; accp[i][2] = bv.z; accp[i][3] = bv.w;
        }
    }
    const float* ps0 = ps + ty * 4 * PS;
    for (int k = 0; k < PD; k += 4) {
        float a[4][4];
        *(float4*)a[0] = *(const float4*)(ps0 + 0 * PS + k);
        *(float4*)a[1] = *(const float4*)(ps0 + 1 * PS + k);
        *(float4*)a[2] = *(const float4*)(ps0 + 2 * PS + k);
        *(float4*)a[3] = *(const float4*)(ps0 + 3 * PS + k);
#pragma unroll
        for (int kk = 0; kk < 4; kk++) {
            float4 w = *(const float4*)(Wp2 + (size_t)(k + kk) * PD + tx * 4);
#pragma unroll
            for (int i = 0; i < 4; i++) {
                float aa = a[i][kk];
                accp[i][0] += aa * w.x; accp[i][1] += aa * w.y;
                accp[i][2] += aa * w.z; accp[i][3] += aa * w.w;
            }
        }
    }
    float inv[4];
    for (int i = 0; i < 4; i++) {
        float ss = accp[i][0] * accp[i][0] + accp[i][1] * accp[i][1] +
                   accp[i][2] * accp[i][2] + accp[i][3] * accp[i][3];
        ss += __shfl_xor(ss, 1, 16);
        ss += __shfl_xor(ss, 2, 16);
        ss += __shfl_xor(ss, 4, 16);
        ss += __shfl_xor(ss, 8, 16);
        inv[i] = 1.0f / fmaxf(sqrtf(ss), 1e-12f);
    }
    __syncthreads();  // everyone done reading p before z overwrites
    for (int i = 0; i < 4; i++) {
        int n = n0 + ty * 4 + i;
        float4 zv;
        zv.x = accp[i][0] * inv[i]; zv.y = accp[i][1] * inv[i];
        zv.z = accp[i][2] * inv[i]; zv.w = accp[i][3] * inv[i];
        *(float4*)(ps + (ty * 4 + i) * PS + tx * 4) = zv;
        if (n < R2) *(float4*)(oz + (size_t)n * PD + tx * 4) = zv;
    }
    __syncthreads();
    // ---- phase 3b: accn += z @ Wn1[DIM:DIM+64]; null = relu(accn) @ Wn2 + bn2
    for (int k = 0; k < PD; k += 4) {
        float a[4][4];
        *(float4*)a[0] = *(const float4*)(ps0 + 0 * PS + k);
        *(float4*)a[1] = *(const float4*)(ps0 + 1 * PS + k);
        *(float4*)a[2] = *(const float4*)(ps0 + 2 * PS + k);
        *(float4*)a[3] = *(const float4*)(ps0 + 3 * PS + k);
#pragma unroll
        for (int kk = 0; kk < 4; kk++) {
            float4 w = *(const float4*)(Wn1 + (size_t)(DIM + k + kk) * PD + tx * 4);
#pragma unroll
            for (int i = 0; i < 4; i++) {
                float aa = a[i][kk];
                accn[i][0] += aa * w.x; accn[i][1] += aa * w.y;
                accn[i][2] += aa * w.z; accn[i][3] += aa * w.w;
            }
        }
    }
    {
        float4 w2 = *(const float4*)(Wn2 + tx * 4);
        float b2v = bn2[0];
        for (int i = 0; i < 4; i++) {
            float r = fmaxf(accn[i][0], 0.f) * w2.x + fmaxf(accn[i][1], 0.f) * w2.y +
                      fmaxf(accn[i][2], 0.f) * w2.z + fmaxf(accn[i][3], 0.f) * w2.w;
            r += __shfl_xor(r, 1, 16);
            r += __shfl_xor(r, 2, 16);
            r += __shfl_xor(r, 4, 16);
            r += __shfl_xor(r, 8, 16);
            int n = n0 + ty * 4 + i;
            if (tx == 0 && n < R2) on[n] = r + b2v;
        }
    }
}

extern "C" void kernel_launch(void* const* d_in, const int* in_sizes, int n_in,
                              void* d_out, int out_size, void* d_ws, size_t ws_size,
                              hipStream_t stream) {
    const float* xA = (const float*)d_in[0];
    const float* xB = (const float*)d_in[1];
    const int* eiA = (const int*)d_in[2];
    const int* eiB = (const int*)d_in[3];
    const float* W1 = (const float*)d_in[4];
    const float* b1 = (const float*)d_in[5];
    const float* W2 = (const float*)d_in[6];
    const float* b2 = (const float*)d_in[7];
    const float* Wp1 = (const float*)d_in[8];
    const float* bp1 = (const float*)d_in[9];
    const float* Wp2 = (const float*)d_in[10];
    const float* bp2 = (const float*)d_in[11];
    const float* Wn1 = (const float*)d_in[12];
    const float* bn1 = (const float*)d_in[13];
    const float* Wn2 = (const float*)d_in[14];
    const float* bn2 = (const float*)d_in[15];

    float* out = (float*)d_out;
    float* outH = out;                            // hA, hB (contiguous 2NN x 128)
    float* outZ = out + (size_t)R2 * DIM;         // zA, zB (contiguous 2NN x 64)
    float* outNull = outZ + (size_t)R2 * PD;      // nullA, nullB (2NN)

    // Workspace (~66 MB), batched over both graphs
    char* w = (char*)d_ws;
    int* deg2 = (int*)w;     w += (((size_t)R2 * 4 + 255) / 256) * 256;
    int* cnt2 = (int*)w;     w += (((size_t)R2 * 4 + 255) / 256) * 256;
    int* excl2 = (int*)w;    w += (((size_t)R2 * 4 + 255) / 256) * 256;
    int* bsum2 = (int*)w;    w += (((size_t)2 * NB1 * 4 + 255) / 256) * 256;
    int* rowptr2 = (int*)w;  w += (((size_t)2 * (NN + 1) * 4 + 255) / 256) * 256;
    float* nrm2 = (float*)w; w += (((size_t)R2 * 4 + 255) / 256) * 256;
    int2* edges2 = (int2*)w; w += (size_t)2 * NE * 8;
    float* h1buf = (float*)w; w += (size_t)R2 * DIM * 4;   // h1 scratch (no outH race)
    if (ws_size < (size_t)(w - (char*)d_ws)) return;  // tripwire: absmax~0.57

    const int GB = (R2 + 63) / 64;  // 1563 dense tiles

    // CSR build, both graphs in one go
    hipMemsetAsync(deg2, 0, (size_t)R2 * 4, stream);
    k_deg<<<(2 * NE + 255) / 256, 256, 0, stream>>>(eiA + NE, eiB + NE, deg2);
    k_scan1<<<2 * NB1, 256, 0, stream>>>(deg2, excl2, bsum2, nrm2);
    k_scan2<<<2, 256, 0, stream>>>(bsum2);
    k_scan3<<<(R2 + 255) / 256, 256, 0, stream>>>(excl2, bsum2, rowptr2, cnt2);
    k_fill<<<(2 * NE + 255) / 256, 256, 0, stream>>>(eiA, eiB, nrm2, cnt2, edges2);

    // Layer 1 fused: gather(x) -> LDS -> @W1 + ReLU -> h1buf (scratch)
    k_gl<1><<<GB, 256, 0, stream>>>(xA, xB, rowptr2, edges2, nrm2, W1, b1, h1buf);

    // Layer 2 fused: gather(h1buf) -> LDS -> @W2 -> outH (h1buf never aliased)
    k_gl<0><<<GB, 256, 0, stream>>>(h1buf, h1buf + (size_t)NN * DIM, rowptr2,
                                    edges2, nrm2, W2, b2, outH);

    // Fused projection + null head, both graphs
    k_head<<<GB, 256, 0, stream>>>(outH, Wp1, bp1, Wp2, bp2, Wn1, bn1, Wn2, bn2,
                                   outZ, outNull);
}

// Round 21
// 794.688 us; speedup vs baseline: 1.3114x; 1.0030x over previous
//
#include <hip/hip_runtime.h>

#define NN 50000
#define NE 800000
#define R2 (2 * NN)      // batched rows (graphs A+B)
#define DIM 128
#define PD 64
#define LS (DIM + 4)     // padded LDS row stride (132): free 2-way aliasing only
#define PS (PD + 4)      // padded p/z stride (68)
#define NB1 ((NN + 255) / 256)  // 196 scan blocks per graph

// ---------- CSR build (batched over both graphs) ----------

__global__ void k_deg(const int* __restrict__ dA, const int* __restrict__ dB,
                      int* __restrict__ deg2) {
    int e = blockIdx.x * blockDim.x + threadIdx.x;
    if (e >= 2 * NE) return;
    int g = e >= NE;
    int d = (g ? dB : dA)[e - g * NE];
    atomicAdd(&deg2[g * NN + d], 1);
}

// scan1 also emits nrm2 = rsqrt(deg+1) from the already-loaded deg value
// (k_norm dispatch folded in; saves a launch + a deg2 re-read).
__global__ void k_scan1(const int* __restrict__ deg2, int* __restrict__ excl2,
                        int* __restrict__ bsum2, float* __restrict__ nrm2) {
    __shared__ int wsum[4];
    int g = blockIdx.x >= NB1;
    int lb = blockIdx.x - g * NB1;
    const int* deg = deg2 + g * NN;
    int tid = threadIdx.x;
    int lane = tid & 63, wid = tid >> 6;
    int i = lb * 256 + tid;
    int v = (i < NN) ? deg[i] : 0;
    if (i < NN) nrm2[g * NN + i] = rsqrtf((float)v + 1.0f);
    int s = v;
    for (int o = 1; o < 64; o <<= 1) {
        int t = __shfl_up(s, o, 64);
        if (lane >= o) s += t;
    }
    if (lane == 63) wsum[wid] = s;
    __syncthreads();
    int woff = 0;
    for (int w = 0; w < wid; w++) woff += wsum[w];
    if (i < NN) excl2[g * NN + i] = woff + s - v;
    if (tid == 255) bsum2[g * NB1 + lb] = woff + s;
}

__global__ void k_scan2(int* __restrict__ bsum2) {
    __shared__ int wsum[4];
    int* bsum = bsum2 + blockIdx.x * NB1;
    int tid = threadIdx.x;
    int lane = tid & 63, wid = tid >> 6;
    int v = (tid < NB1) ? bsum[tid] : 0;
    int s = v;
    for (int o = 1; o < 64; o <<= 1) {
        int t = __shfl_up(s, o, 64);
        if (lane >= o) s += t;
    }
    if (lane == 63) wsum[wid] = s;
    __syncthreads();
    int woff = 0;
    for (int w = 0; w < wid; w++) woff += wsum[w];
    if (tid < NB1) bsum[tid] = woff + s - v;
}

// rowptr and cnt both get the row-start offset; cnt then serves as the
// running absolute fill cursor in k_fill (saves a rowptr read per edge).
__global__ void k_scan3(const int* __restrict__ excl2, const int* __restrict__ bsum2,
                        int* __restrict__ rowptr2, int* __restrict__ cnt2) {
    int i = blockIdx.x * blockDim.x + threadIdx.x;
    if (i >= R2) return;
    int g = i >= NN;
    int il = i - g * NN;
    int start = excl2[i] + bsum2[g * NB1 + (il >> 8)];
    rowptr2[g * (NN + 1) + il] = start;
    cnt2[i] = start;
    if (il == 0) rowptr2[g * (NN + 1) + NN] = NE;
}

__global__ void k_fill(const int* __restrict__ eA, const int* __restrict__ eB,
                       const float* __restrict__ nrm2,
                       int* __restrict__ cnt2, int2* __restrict__ edges2) {
    int e = blockIdx.x * blockDim.x + threadIdx.x;
    if (e >= 2 * NE) return;
    int g = e >= NE;
    const int* ei = g ? eB : eA;
    int ee = e - g * NE;
    int s = ei[ee], d = ei[NE + ee];
    const float* nrm = nrm2 + g * NN;
    int pos = atomicAdd(&cnt2[g * NN + d], 1);  // absolute slot (cnt pre-seeded)
    int2 rec;
    rec.x = s;
    rec.y = __float_as_int(nrm[s] * nrm[d]);
    edges2[(size_t)g * NE + pos] = rec;
}

// ---------- R15: FUSED gather + dense layer ----------
// Occupancy attacks on the dense kernels are dead (R5/R8/R15: all spill).
// Instead kill the agg2 round-trip: each 64-row block gathers its nodes
// DIRECTLY into the GEMM's LDS tile (wave w handles 16 nodes sequentially;
// per-node body identical to the old k_gather incl. 8-edge unroll), then runs
// the verified k_layer GEMM body. Saves 51MB write + 51MB read per layer plus
// 2 launches. Buffers re-plumbed to avoid in-place races: layer1 x->h1buf,
// layer2 h1buf->outH (never reads outH).
// R19: fused config passed at 797us (best), absmax identical. k_head measured
// 213us vs verified 175.5 with identical counters and proportionally lower
// hbm_gbps -> clock-throttled run suspected; this is the clock-normalized
// confirmation measurement.
template <int RELU>
__global__ __launch_bounds__(256) void k_gl(
    const float* __restrict__ x0, const float* __restrict__ x1,
    const int* __restrict__ rowptr2, const int2* __restrict__ edges2,
    const float* __restrict__ nrm2,
    const float* __restrict__ W, const float* __restrict__ b,
    float* __restrict__ C) {
    __shared__ float As[64 * LS];  // 33 KB gathered tile
    int tid = threadIdx.x;
    int lane = tid & 63, wid = tid >> 6;  // 4 waves
    int n0 = blockIdx.x * 64;
    // ---- phase A: gather 16 nodes per wave into As rows ----
    int half = lane >> 5;  // 0/1: even/odd edge of a pair
    int hl = lane & 31;    // dims hl*4 .. hl*4+3
    for (int j = 0; j < 16; j++) {
        int n = n0 + wid * 16 + j;  // wave-uniform
        if (n >= R2) break;         // last block: 32 pad rows (stores guarded)
        int g = n >= NN;
        int nl = n - g * NN;
        const float* x = g ? x1 : x0;
        const int* rowptr = rowptr2 + g * (NN + 1);
        const int2* edges = edges2 + (size_t)g * NE;
        int beg = rowptr[nl], end = rowptr[nl + 1];
        float4 a = {0.f, 0.f, 0.f, 0.f};
        float4 bb = {0.f, 0.f, 0.f, 0.f};
        int i = beg;
        for (; i + 7 < end; i += 8) {  // 8 edges/iter, 4 per half-wave
            int2 r0 = edges[i + half];
            int2 r1 = edges[i + 2 + half];
            int2 r2 = edges[i + 4 + half];
            int2 r3 = edges[i + 6 + half];
            float4 v0 = *(const float4*)(x + (size_t)r0.x * DIM + hl * 4);
            float4 v1 = *(const float4*)(x + (size_t)r1.x * DIM + hl * 4);
            float4 v2 = *(const float4*)(x + (size_t)r2.x * DIM + hl * 4);
            float4 v3 = *(const float4*)(x + (size_t)r3.x * DIM + hl * 4);
            float c0 = __int_as_float(r0.y), c1 = __int_as_float(r1.y);
            float c2 = __int_as_float(r2.y), c3 = __int_as_float(r3.y);
            a.x += v0.x * c0 + v1.x * c1;  bb.x += v2.x * c2 + v3.x * c3;
            a.y += v0.y * c0 + v1.y * c1;  bb.y += v2.y * c2 + v3.y * c3;
            a.z += v0.z * c0 + v1.z * c1;  bb.z += v2.z * c2 + v3.z * c3;
            a.w += v0.w * c0 + v1.w * c1;  bb.w += v2.w * c2 + v3.w * c3;
        }
        for (; i + 3 < end; i += 4) {
            int2 r0 = edges[i + half];
            int2 r1 = edges[i + 2 + half];
            float4 v0 = *(const float4*)(x + (size_t)r0.x * DIM + hl * 4);
            float4 v1 = *(const float4*)(x + (size_t)r1.x * DIM + hl * 4);
            float c0 = __int_as_float(r0.y), c1 = __int_as_float(r1.y);
            a.x += v0.x * c0 + v1.x * c1;
            a.y += v0.y * c0 + v1.y * c1;
            a.z += v0.z * c0 + v1.z * c1;
            a.w += v0.w * c0 + v1.w * c1;
        }
        for (; i + 1 < end; i += 2) {
            int2 r0 = edges[i + half];
            float4 v0 = *(const float4*)(x + (size_t)r0.x * DIM + hl * 4);
            float c0 = __int_as_float(r0.y);
            a.x += v0.x * c0; a.y += v0.y * c0;
            a.z += v0.z * c0; a.w += v0.w * c0;
        }
        if (i < end && half == 0) {
            int2 r0 = edges[i];
            float4 v0 = *(const float4*)(x + (size_t)r0.x * DIM + hl * 4);
            float c0 = __int_as_float(r0.y);
            a.x += v0.x * c0; a.y += v0.y * c0;
            a.z += v0.z * c0; a.w += v0.w * c0;
        }
        a.x += bb.x; a.y += bb.y; a.z += bb.z; a.w += bb.w;
        a.x += __shfl_xor(a.x, 32, 64);
        a.y += __shfl_xor(a.y, 32, 64);
        a.z += __shfl_xor(a.z, 32, 64);
        a.w += __shfl_xor(a.w, 32, 64);
        if (half == 0) {  // self-loop + write LDS row (32 lanes x 16B = 512B)
            float nm = nrm2[n];
            float cs = nm * nm;
            float4 xv = *(const float4*)(x + (size_t)nl * DIM + hl * 4);
            float4 o;
            o.x = a.x + xv.x * cs;
            o.y = a.y + xv.y * cs;
            o.z = a.z + xv.z * cs;
            o.w = a.w + xv.w * cs;
            *(float4*)(As + (n - n0) * LS + hl * 4) = o;
        }
    }
    __syncthreads();
    // ---- phase B: verified k_layer GEMM body (64 rows x 128, acc[4][8]) ----
    int tx = tid & 15, ty = tid >> 4;
    float acc[4][8];
    {
        const float4* bg = (const float4*)(b + tx * 8);
        float4 b0 = bg[0], b1 = bg[1];
        for (int i = 0; i < 4; i++) {
            acc[i][0] = b0.x; acc[i][1] = b0.y; acc[i][2] = b0.z; acc[i][3] = b0.w;
            acc[i][4] = b1.x; acc[i][5] = b1.y; acc[i][6] = b1.z; acc[i][7] = b1.w;
        }
    }
    const float* As0 = As + ty * 4 * LS;
    for (int k = 0; k < DIM; k += 4) {
        float a[4][4];
        *(float4*)a[0] = *(const float4*)(As0 + 0 * LS + k);
        *(float4*)a[1] = *(const float4*)(As0 + 1 * LS + k);
        *(float4*)a[2] = *(const float4*)(As0 + 2 * LS + k);
        *(float4*)a[3] = *(const float4*)(As0 + 3 * LS + k);
#pragma unroll
        for (int kk = 0; kk < 4; kk++) {
            float4 w0 = *(const float4*)(W + (size_t)(k + kk) * DIM + tx * 8);
            float4 w1 = *(const float4*)(W + (size_t)(k + kk) * DIM + tx * 8 + 4);
#pragma unroll
            for (int i = 0; i < 4; i++) {
                float aa = a[i][kk];
                acc[i][0] += aa * w0.x; acc[i][1] += aa * w0.y;
                acc[i][2] += aa * w0.z; acc[i][3] += aa * w0.w;
                acc[i][4] += aa * w1.x; acc[i][5] += aa * w1.y;
                acc[i][6] += aa * w1.z; acc[i][7] += aa * w1.w;
            }
        }
    }
    for (int i = 0; i < 4; i++) {
        int n = n0 + ty * 4 + i;
        if (n >= R2) break;
        float4 o0, o1;
        o0.x = acc[i][0]; o0.y = acc[i][1]; o0.z = acc[i][2]; o0.w = acc[i][3];
        o1.x = acc[i][4]; o1.y = acc[i][5]; o1.z = acc[i][6]; o1.w = acc[i][7];
        if (RELU) {
            o0.x = fmaxf(o0.x, 0.f); o0.y = fmaxf(o0.y, 0.f);
            o0.z = fmaxf(o0.z, 0.f); o0.w = fmaxf(o0.w, 0.f);
            o1.x = fmaxf(o1.x, 0.f); o1.y = fmaxf(o1.y, 0.f);
            o1.z = fmaxf(o1.z, 0.f); o1.w = fmaxf(o1.w, 0.f);
        }
        *(float4*)(C + (size_t)n * DIM + tx * 8) = o0;
        *(float4*)(C + (size_t)n * DIM + tx * 8 + 4) = o1;
    }
}

// Fused head over both graphs: p=relu(h@Wp1+bp1); q=p@Wp2+bp2; z=l2norm(q);
// null = relu([h,z]@Wn1+bn1) @ Wn2 + bn2.
// R6 form, verified 175us three times: 256 thr x 4 rows, h@Wp1 + h@Wn1[0:128]
// fused in one h-scan, weights direct from L2, VGPR=256. Occupancy attacks
// (R5 cap, R8 LDS-stage, R15 512-thr) ALL spilled — do not retry.
__global__ __launch_bounds__(256) void k_head(
    const float* __restrict__ h, const float* __restrict__ Wp1,
    const float* __restrict__ bp1, const float* __restrict__ Wp2,
    const float* __restrict__ bp2, const float* __restrict__ Wn1,
    const float* __restrict__ bn1, const float* __restrict__ Wn2,
    const float* __restrict__ bn2, float* __restrict__ oz, float* __restrict__ on) {
    __shared__ float hs[64 * LS];  // 33 KB
    __shared__ float ps[64 * PS];  // 17 KB (p, then reused for z)
    int tid = threadIdx.x;
    int tx = tid & 15, ty = tid >> 4;
    int n0 = blockIdx.x * 64;
    {
        const float4* hg = (const float4*)(h + (size_t)n0 * DIM);
        int lim = (R2 - n0) * (DIM / 4);
        for (int i = tid; i < 64 * DIM / 4; i += 256) {
            float4 v = {0.f, 0.f, 0.f, 0.f};
            if (i < lim) v = hg[i];
            *(float4*)(hs + (i >> 5) * LS + (i & 31) * 4) = v;
        }
    }
    __syncthreads();
    const float* hs0 = hs + ty * 4 * LS;
    float accp[4][4];  // p accumulator (reused for q in phase 2)
    float accn[4][4];  // null-head accumulator, persistent across phases
    // ---- fused phase 1+3a: accp = h @ Wp1 + bp1 ; accn = h @ Wn1[0:128] + bn1
    {
        float4 bv = *(const float4*)(bp1 + tx * 4);
        float4 nv = *(const float4*)(bn1 + tx * 4);
        for (int i = 0; i < 4; i++) {
            accp[i][0] = bv.x; accp[i][1] = bv.y; accp[i][2] = bv.z; accp[i][3] = bv.w;
            accn[i][0] = nv.x; accn[i][1] = nv.y; accn[i][2] = nv.z; accn[i][3] = nv.w;
        }
    }
    for (int k = 0; k < DIM; k += 4) {
        float a[4][4];
        *(float4*)a[0] = *(const float4*)(hs0 + 0 * LS + k);
        *(float4*)a[1] = *(const float4*)(hs0 + 1 * LS + k);
        *(float4*)a[2] = *(const float4*)(hs0 + 2 * LS + k);
        *(float4*)a[3] = *(const float4*)(hs0 + 3 * LS + k);
#pragma unroll
        for (int kk = 0; kk < 4; kk++) {
            float4 wp = *(const float4*)(Wp1 + (size_t)(k + kk) * PD + tx * 4);
            float4 wn = *(const float4*)(Wn1 + (size_t)(k + kk) * PD + tx * 4);
#pragma unroll
            for (int i = 0; i < 4; i++) {
                float aa = a[i][kk];
                accp[i][0] += aa * wp.x; accp[i][1] += aa * wp.y;
                accp[i][2] += aa * wp.z; accp[i][3] += aa * wp.w;
                accn[i][0] += aa * wn.x; accn[i][1] += aa * wn.y;
                accn[i][2] += aa * wn.z; accn[i][3] += aa * wn.w;
            }
        }
    }
    for (int i = 0; i < 4; i++) {
        float4 pv;
        pv.x = fmaxf(accp[i][0], 0.f); pv.y = fmaxf(accp[i][1], 0.f);
        pv.z = fmaxf(accp[i][2], 0.f); pv.w = fmaxf(accp[i][3], 0.f);
        *(float4*)(ps + (ty * 4 + i) * PS + tx * 4) = pv;
    }
    __syncthreads();
    // ---- phase 2: q = p @ Wp2 + bp2, row l2norm ----
    {
        float4 bv = *(const float4*)(bp2 + tx * 4);
        for (int i = 0; i < 4; i++) {
            accp[i][0] = bv.x; accp[i][1] = bv.y; accp[i][2] = bv.z; accp[i][3] = bv.w;
        }
    }
    const float* ps0 = ps + ty * 4 * PS;
    for (int k = 0; k < PD; k += 4) {
        float a[4][4];
        *(float4*)a[0] = *(const float4*)(ps0 + 0 * PS + k);
        *(float4*)a[1] = *(const float4*)(ps0 + 1 * PS + k);
        *(float4*)a[2] = *(const float4*)(ps0 + 2 * PS + k);
        *(float4*)a[3] = *(const float4*)(ps0 + 3 * PS + k);
#pragma unroll
        for (int kk = 0; kk < 4; kk++) {
            float4 w = *(const float4*)(Wp2 + (size_t)(k + kk) * PD + tx * 4);
#pragma unroll
            for (int i = 0; i < 4; i++) {
                float aa = a[i][kk];
                accp[i][0] += aa * w.x; accp[i][1] += aa * w.y;
                accp[i][2] += aa * w.z; accp[i][3] += aa * w.w;
            }
        }
    }
    float inv[4];
    for (int i = 0; i < 4; i++) {
        float ss = accp[i][0] * accp[i][0] + accp[i][1] * accp[i][1] +
                   accp[i][2] * accp[i][2] + accp[i][3] * accp[i][3];
        ss += __shfl_xor(ss, 1, 16);
        ss += __shfl_xor(ss, 2, 16);
        ss += __shfl_xor(ss, 4, 16);
        ss += __shfl_xor(ss, 8, 16);
        inv[i] = 1.0f / fmaxf(sqrtf(ss), 1e-12f);
    }
    __syncthreads();  // everyone done reading p before z overwrites
    for (int i = 0; i < 4; i++) {
        int n = n0 + ty * 4 + i;
        float4 zv;
        zv.x = accp[i][0] * inv[i]; zv.y = accp[i][1] * inv[i];
        zv.z = accp[i][2] * inv[i]; zv.w = accp[i][3] * inv[i];
        *(float4*)(ps + (ty * 4 + i) * PS + tx * 4) = zv;
        if (n < R2) *(float4*)(oz + (size_t)n * PD + tx * 4) = zv;
    }
    __syncthreads();
    // ---- phase 3b: accn += z @ Wn1[DIM:DIM+64]; null = relu(accn) @ Wn2 + bn2
    for (int k = 0; k < PD; k += 4) {
        float a[4][4];
        *(float4*)a[0] = *(const float4*)(ps0 + 0 * PS + k);
        *(float4*)a[1] = *(const float4*)(ps0 + 1 * PS + k);
        *(float4*)a[2] = *(const float4*)(ps0 + 2 * PS + k);
        *(float4*)a[3] = *(const float4*)(ps0 + 3 * PS + k);
#pragma unroll
        for (int kk = 0; kk < 4; kk++) {
            float4 w = *(const float4*)(Wn1 + (size_t)(DIM + k + kk) * PD + tx * 4);
#pragma unroll
            for (int i = 0; i < 4; i++) {
                float aa = a[i][kk];
                accn[i][0] += aa * w.x; accn[i][1] += aa * w.y;
                accn[i][2] += aa * w.z; accn[i][3] += aa * w.w;
            }
        }
    }
    {
        float4 w2 = *(const float4*)(Wn2 + tx * 4);
        float b2v = bn2[0];
        for (int i = 0; i < 4; i++) {
            float r = fmaxf(accn[i][0], 0.f) * w2.x + fmaxf(accn[i][1], 0.f) * w2.y +
                      fmaxf(accn[i][2], 0.f) * w2.z + fmaxf(accn[i][3], 0.f) * w2.w;
            r += __shfl_xor(r, 1, 16);
            r += __shfl_xor(r, 2, 16);
            r += __shfl_xor(r, 4, 16);
            r += __shfl_xor(r, 8, 16);
            int n = n0 + ty * 4 + i;
            if (tx == 0 && n < R2) on[n] = r + b2v;
        }
    }
}

extern "C" void kernel_launch(void* const* d_in, const int* in_sizes, int n_in,
                              void* d_out, int out_size, void* d_ws, size_t ws_size,
                              hipStream_t stream) {
    const float* xA = (const float*)d_in[0];
    const float* xB = (const float*)d_in[1];
    const int* eiA = (const int*)d_in[2];
    const int* eiB = (const int*)d_in[3];
    const float* W1 = (const float*)d_in[4];
    const float* b1 = (const float*)d_in[5];
    const float* W2 = (const float*)d_in[6];
    const float* b2 = (const float*)d_in[7];
    const float* Wp1 = (const float*)d_in[8];
    const float* bp1 = (const float*)d_in[9];
    const float* Wp2 = (const float*)d_in[10];
    const float* bp2 = (const float*)d_in[11];
    const float* Wn1 = (const float*)d_in[12];
    const float* bn1 = (const float*)d_in[13];
    const float* Wn2 = (const float*)d_in[14];
    const float* bn2 = (const float*)d_in[15];

    float* out = (float*)d_out;
    float* outH = out;                            // hA, hB (contiguous 2NN x 128)
    float* outZ = out + (size_t)R2 * DIM;         // zA, zB (contiguous 2NN x 64)
    float* outNull = outZ + (size_t)R2 * PD;      // nullA, nullB (2NN)

    // Workspace (~66 MB), batched over both graphs
    char* w = (char*)d_ws;
    int* deg2 = (int*)w;     w += (((size_t)R2 * 4 + 255) / 256) * 256;
    int* cnt2 = (int*)w;     w += (((size_t)R2 * 4 + 255) / 256) * 256;
    int* excl2 = (int*)w;    w += (((size_t)R2 * 4 + 255) / 256) * 256;
    int* bsum2 = (int*)w;    w += (((size_t)2 * NB1 * 4 + 255) / 256) * 256;
    int* rowptr2 = (int*)w;  w += (((size_t)2 * (NN + 1) * 4 + 255) / 256) * 256;
    float* nrm2 = (float*)w; w += (((size_t)R2 * 4 + 255) / 256) * 256;
    int2* edges2 = (int2*)w; w += (size_t)2 * NE * 8;
    float* h1buf = (float*)w; w += (size_t)R2 * DIM * 4;   // h1 scratch (no outH race)
    if (ws_size < (size_t)(w - (char*)d_ws)) return;  // tripwire: absmax~0.57

    const int GB = (R2 + 63) / 64;  // 1563 dense tiles

    // CSR build, both graphs in one go
    hipMemsetAsync(deg2, 0, (size_t)R2 * 4, stream);
    k_deg<<<(2 * NE + 255) / 256, 256, 0, stream>>>(eiA + NE, eiB + NE, deg2);
    k_scan1<<<2 * NB1, 256, 0, stream>>>(deg2, excl2, bsum2, nrm2);
    k_scan2<<<2, 256, 0, stream>>>(bsum2);
    k_scan3<<<(R2 + 255) / 256, 256, 0, stream>>>(excl2, bsum2, rowptr2, cnt2);
    k_fill<<<(2 * NE + 255) / 256, 256, 0, stream>>>(eiA, eiB, nrm2, cnt2, edges2);

    // Layer 1 fused: gather(x) -> LDS -> @W1 + ReLU -> h1buf (scratch)
    k_gl<1><<<GB, 256, 0, stream>>>(xA, xB, rowptr2, edges2, nrm2, W1, b1, h1buf);

    // Layer 2 fused: gather(h1buf) -> LDS -> @W2 -> outH (h1buf never aliased)
    k_gl<0><<<GB, 256, 0, stream>>>(h1buf, h1buf + (size_t)NN * DIM, rowptr2,
                                    edges2, nrm2, W2, b2, outH);

    // Fused projection + null head, both graphs
    k_head<<<GB, 256, 0, stream>>>(outH, Wp1, bp1, Wp2, bp2, Wn1, bn1, Wn2, bn2,
                                   outZ, outNull);
}